// Round 4
// baseline (531.879 us; speedup 1.0000x reference)
//
#include <hip/hip_runtime.h>
#include <math.h>

#define NFFT  8192
#define L_SEQ 8192
#define NC    256
#define NTH   512

typedef float2 cplx;

__device__ __forceinline__ cplx cmul(cplx a, cplx b){
    return make_float2(fmaf(a.x,b.x,-(a.y*b.y)), fmaf(a.x,b.y,a.y*b.x));
}
__device__ __forceinline__ cplx cadd(cplx a, cplx b){ return make_float2(a.x+b.x,a.y+b.y); }
__device__ __forceinline__ cplx csub(cplx a, cplx b){ return make_float2(a.x-b.x,a.y-b.y); }
// bank swizzle: float2 element e -> slot e ^ ((e>>4)&15)
__device__ __forceinline__ int swz(int e){ return e ^ ((e>>4)&15); }
// in-register digit reversal of dft16_ip output: slot j holds frequency sig(j)
__device__ __forceinline__ constexpr int sig(int j){ return ((j&3)<<2) | (j>>2); }

#define C16f 0.9238795325112867f
#define S16f 0.3826834323650898f
#define RH   0.7071067811865476f
#define PI2F 6.28318530717958647692f

template<bool INV>
__device__ __forceinline__ void radix4(cplx& A0, cplx& A1, cplx& A2, cplx& A3){
    cplx t0=cadd(A0,A2), t1=csub(A0,A2), t2=cadd(A1,A3), t3=csub(A1,A3);
    A0=cadd(t0,t2); A2=csub(t0,t2);
    if(!INV){ A1=make_float2(t1.x+t3.y,t1.y-t3.x); A3=make_float2(t1.x-t3.y,t1.y+t3.x); }
    else    { A1=make_float2(t1.x-t3.y,t1.y+t3.x); A3=make_float2(t1.x+t3.y,t1.y-t3.x); }
}
template<bool INV>
__device__ __forceinline__ cplx twid(cplx v, float re, float im){
    return INV ? cmul(v, make_float2(re,  im)) : cmul(v, make_float2(re, -im));
}
template<bool INV>
__device__ __forceinline__ cplx mulmi(cplx v){
    return INV ? make_float2(-v.y, v.x) : make_float2(v.y, -v.x);
}
template<bool INV>
__device__ __forceinline__ void dft16_twiddles(cplx v[16]){
    v[5] = twid<INV>(v[5], C16f,S16f);    // n0=1,k0=1
    v[9] = twid<INV>(v[9], RH,RH);        // n0=1,k0=2
    v[13]= twid<INV>(v[13],S16f,C16f);    // n0=1,k0=3
    v[6] = twid<INV>(v[6], RH,RH);        // n0=2,k0=1
    v[10]= mulmi<INV>(v[10]);             // n0=2,k0=2
    v[14]= twid<INV>(v[14],-RH,RH);       // n0=2,k0=3
    v[7] = twid<INV>(v[7], S16f,C16f);    // n0=3,k0=1
    v[11]= twid<INV>(v[11],-RH,RH);       // n0=3,k0=2
    v[15]= twid<INV>(v[15],-C16f,-S16f);  // n0=3,k0=3
}
// In-place DFT-16: no transpose scratch. Output: slot j holds frequency sig(j).
template<bool INV>
__device__ __forceinline__ void dft16_ip(cplx v[16]){
    #pragma unroll
    for(int n0=0;n0<4;n0++) radix4<INV>(v[n0], v[n0+4], v[n0+8], v[n0+12]);
    dft16_twiddles<INV>(v);
    #pragma unroll
    for(int k0=0;k0<4;k0++) radix4<INV>(v[4*k0], v[4*k0+1], v[4*k0+2], v[4*k0+3]);
}
// forward, v[8..15] implicitly zero on input
__device__ __forceinline__ void dft16_half_ip(cplx v[16]){
    #pragma unroll
    for(int n0=0;n0<4;n0++){
        cplx a=v[n0], b=v[n0+4];
        v[n0]    = cadd(a,b);
        v[n0+4]  = make_float2(a.x+b.y, a.y-b.x);
        v[n0+8]  = csub(a,b);
        v[n0+12] = make_float2(a.x-b.y, a.y+b.x);
    }
    dft16_twiddles<false>(v);
    #pragma unroll
    for(int k0=0;k0<4;k0++) radix4<false>(v[4*k0], v[4*k0+1], v[4*k0+2], v[4*k0+3]);
}
// v[m] *= exp(i*th1*m), natural order (used BEFORE inverse dft16_ip)
__device__ __forceinline__ void stwiddle(cplx v[16], float th1){
    float s,c; __sincosf(th1,&s,&c);
    cplx w=make_float2(c,s), wm=w;
    v[1]=cmul(v[1],wm);
    #pragma unroll
    for(int m=2;m<16;m++){ wm=cmul(wm,w); v[m]=cmul(v[m],wm); }
}
// v[j] *= exp(i*th1*sig(j)) (used AFTER forward dft16_ip; exponent = slot's frequency)
__device__ __forceinline__ void stwiddle_rev(cplx v[16], float th1){
    float s,c; __sincosf(th1,&s,&c);
    cplx w=make_float2(c,s);
    cplx w2=cmul(w,w);
    cplx w4=cmul(w2,w2);
    cplx t=w4;                      // j=1..3: exp 4,8,12
    v[1]=cmul(v[1],t); t=cmul(t,w4); v[2]=cmul(v[2],t); t=cmul(t,w4); v[3]=cmul(v[3],t);
    t=w;                            // j=4..7: exp 1,5,9,13
    v[4]=cmul(v[4],t); t=cmul(t,w4); v[5]=cmul(v[5],t); t=cmul(t,w4); v[6]=cmul(v[6],t); t=cmul(t,w4); v[7]=cmul(v[7],t);
    t=w2;                           // j=8..11: exp 2,6,10,14
    v[8]=cmul(v[8],t); t=cmul(t,w4); v[9]=cmul(v[9],t); t=cmul(t,w4); v[10]=cmul(v[10],t); t=cmul(t,w4); v[11]=cmul(v[11],t);
    t=cmul(w2,w);                   // j=12..15: exp 3,7,11,15
    v[12]=cmul(v[12],t); t=cmul(t,w4); v[13]=cmul(v[13],t); t=cmul(t,w4); v[14]=cmul(v[14],t); t=cmul(t,w4); v[15]=cmul(v[15],t);
}

template<bool INV>
__device__ __forceinline__ void stageB(cplx* z, int t){
    const int q=t&31, bb=t>>5, base=512*bb+q;
    cplx v[16];
    #pragma unroll
    for(int m=0;m<16;m++) v[m]=z[swz(base+32*m)];
    if(INV){
        stwiddle(v, (PI2F/512.f)*(float)q);
        dft16_ip<true>(v);
    }else{
        dft16_ip<false>(v);
        stwiddle_rev(v, -(PI2F/512.f)*(float)q);
    }
    #pragma unroll
    for(int j=0;j<16;j++) z[swz(base+32*sig(j))]=v[j];
}
// forward: radix-16 (Lc=32) then fused radix-2 (Lc=2) via lane shfl
__device__ __forceinline__ void stageCD_fwd(cplx* z, int t){
    const int q=t&1, bb=t>>1, base=32*bb+q;
    cplx v[16];
    #pragma unroll
    for(int m=0;m<16;m++) v[m]=z[swz(base+2*m)];
    dft16_ip<false>(v);
    stwiddle_rev(v, -(PI2F/32.f)*(float)q);
    const float sg = q ? -1.f : 1.f;
    #pragma unroll
    for(int j=0;j<16;j++){
        float ox=__shfl_xor(v[j].x,1), oy=__shfl_xor(v[j].y,1);
        v[j]=make_float2(fmaf(sg,v[j].x,ox), fmaf(sg,v[j].y,oy));
        z[swz(base+2*sig(j))]=v[j];
    }
}
// inverse: fused radix-2 first, then radix-16 (Lc=32)
__device__ __forceinline__ void stageDC_inv(cplx* z, int t){
    const int q=t&1, bb=t>>1, base=32*bb+q;
    cplx v[16];
    #pragma unroll
    for(int m=0;m<16;m++) v[m]=z[swz(base+2*m)];
    const float sg = q ? -1.f : 1.f;
    #pragma unroll
    for(int m=0;m<16;m++){
        float ox=__shfl_xor(v[m].x,1), oy=__shfl_xor(v[m].y,1);
        v[m]=make_float2(fmaf(sg,v[m].x,ox), fmaf(sg,v[m].y,oy));
    }
    stwiddle(v, (PI2F/32.f)*(float)q);
    dft16_ip<true>(v);
    #pragma unroll
    for(int j=0;j<16;j++) z[swz(base+2*sig(j))]=v[j];
}
// position of frequency f after DIF digit-reversal (radices 16,16,16,2)
__device__ __forceinline__ int posf(int f){
    return 512*(f&15) + 32*((f>>4)&15) + 2*((f>>8)&15) + (f>>12);
}

__global__ __launch_bounds__(NTH)
void fftconv_kernel(const float* __restrict__ x,
                    const float* __restrict__ kern,
                    float* __restrict__ out){
    extern __shared__ cplx z[];   // 8192 cplx = 64 KB
    const int t  = threadIdx.x;
    const int c  = blockIdx.x >> 1;
    const int bh = blockIdx.x & 1;
    const int A  = t & 15, B = t >> 4;
    const float inv_n = 1.0f/NFFT;

    // ---- kern: smooth(window 7, reflect) + soft-threshold -> LDS natural ----
    {
        const float* kr = kern + (size_t)c * L_SEQ;
        float buf[22];
        #pragma unroll
        for(int j=0;j<22;j++){
            int idx = 16*t + j - 3;
            idx = idx < 0 ? -idx : idx;
            idx = idx >= L_SEQ ? 2*L_SEQ-2-idx : idx;
            buf[j] = kr[idx];
        }
        float v16[16];
        float s = buf[0]+buf[1]+buf[2]+buf[3]+buf[4]+buf[5]+buf[6];
        v16[0]=s;
        #pragma unroll
        for(int j=1;j<16;j++){ s += buf[j+6]-buf[j-1]; v16[j]=s; }
        #pragma unroll
        for(int j=0;j<16;j++){
            float sv=v16[j]*(1.f/7.f);
            float a=fabsf(sv)-0.003f;
            v16[j]= a>0.f ? copysignf(a,sv) : 0.f;
        }
        #pragma unroll
        for(int e=0;e<8;e++) z[swz(8*t+e)] = make_float2(v16[2*e], v16[2*e+1]);
    }
    __syncthreads();
    // kern forward FFT: stage A (half input from LDS), B, C+D
    {
        cplx v[16];
        #pragma unroll
        for(int m=0;m<8;m++) v[m]=z[swz(t+512*m)];
        __syncthreads();   // all reads done before overwriting (different slots per thread)
        dft16_half_ip(v);
        stwiddle_rev(v, -(PI2F/8192.f)*(float)t);
        #pragma unroll
        for(int j=0;j<16;j++) z[swz(t+512*sig(j))]=v[j];
    }
    __syncthreads();
    stageB<false>(z,t);
    __syncthreads();
    stageCD_fwd(z,t);
    __syncthreads();

    // ---- kern rfft bins -> registers (f = 256A + 8B + it), 1/N folded in ----
    cplx kA[8], kB[8];
    cplx kA8 = make_float2(0.f, 0.f);
    #pragma unroll
    for(int it=0; it<8; ++it){
        const int f = 256*A + 8*B + it;
        const int g = (NFFT - f) & (NFFT-1);
        const cplx Zf = z[swz(posf(f))];
        const cplx Zg = z[swz(posf(g))];
        float s,cc; __sincosf((PI2F*0.5f/NFFT)*(float)f,&s,&cc);
        cplx E = make_float2(0.5f*(Zf.x+Zg.x), 0.5f*(Zf.y-Zg.y));
        cplx O = make_float2(0.5f*(Zf.y+Zg.y), -0.5f*(Zf.x-Zg.x));
        cplx a = cadd(E, cmul(make_float2(cc,-s), O));
        cplx b = cadd(make_float2(E.x,-E.y), cmul(make_float2(-cc,-s), make_float2(O.x,-O.y)));
        kA[it] = make_float2(a.x*inv_n, a.y*inv_n);
        kB[it] = make_float2(b.x*inv_n, b.y*inv_n);
    }
    if(t==0){
        const cplx Zf = z[swz(1)];           // f=4096: posf=1, K=conj(Z)
        kA8 = make_float2(Zf.x*inv_n, -Zf.y*inv_n);
    }

    // ---- 4 batch rows ----
    for(int bi=0;bi<4;bi++){
        const int b = bh*4 + bi;
        __syncthreads();
        // forward stage A fused with global read (upper half zero)
        {
            const cplx* xr = (const cplx*)(x + ((size_t)b*NC + c)*L_SEQ);
            cplx v[16];
            #pragma unroll
            for(int m=0;m<8;m++) v[m]=xr[t+512*m];
            dft16_half_ip(v);
            stwiddle_rev(v, -(PI2F/8192.f)*(float)t);
            #pragma unroll
            for(int j=0;j<16;j++) z[swz(t+512*sig(j))]=v[j];
        }
        __syncthreads();
        stageB<false>(z,t);
        __syncthreads();
        stageCD_fwd(z,t);
        __syncthreads();
        // pointwise multiply in digit-reversed positions; (f, N-f) pair per thread
        #pragma unroll
        for(int it=0; it<8; ++it){
            const int f  = 256*A + 8*B + it;
            const int g  = (NFFT - f) & (NFFT-1);
            const int pf = posf(f), pg = posf(g);
            const cplx Zf = z[swz(pf)];
            const cplx Zg = z[swz(pg)];
            float s,cc; __sincosf((PI2F*0.5f/NFFT)*(float)f,&s,&cc);
            cplx E = make_float2(0.5f*(Zf.x+Zg.x), 0.5f*(Zf.y-Zg.y));
            cplx O = make_float2(0.5f*(Zf.y+Zg.y), -0.5f*(Zf.x-Zg.x));
            cplx Xf = cadd(E, cmul(make_float2(cc,-s), O));
            cplx Xg = cadd(make_float2(E.x,-E.y), cmul(make_float2(-cc,-s), make_float2(O.x,-O.y)));
            cplx Yf = cmul(Xf, kA[it]);
            cplx Yg = cmul(Xg, kB[it]);
            cplx P = make_float2(0.5f*(Yf.x+Yg.x), 0.5f*(Yf.y-Yg.y));
            cplx Q = make_float2(0.5f*(Yf.x-Yg.x), 0.5f*(Yf.y+Yg.y));
            z[swz(pf)] = cadd(P, cmul(make_float2(-s,cc),Q));
            if(f!=0){
                cplx Pg = make_float2(P.x,-P.y);
                cplx Qg = make_float2(-Q.x,Q.y);
                z[swz(pg)] = cadd(Pg, cmul(make_float2(-s,-cc),Qg));
            }
        }
        if(t==0){
            const cplx Zf = z[swz(1)];
            const cplx Y  = cmul(make_float2(Zf.x,-Zf.y), kA8);
            z[swz(1)] = make_float2(Y.x, -Y.y);
        }
        __syncthreads();
        stageDC_inv(z,t);
        __syncthreads();
        stageB<true>(z,t);
        __syncthreads();
        // inverse stage A' fused with global write (only low 8 outputs needed)
        {
            cplx v[16];
            #pragma unroll
            for(int m=0;m<16;m++) v[m]=z[swz(t+512*m)];
            stwiddle(v, (PI2F/8192.f)*(float)t);
            // in-place inverse dft16, stage 1 + twiddles
            #pragma unroll
            for(int n0=0;n0<4;n0++) radix4<true>(v[n0], v[n0+4], v[n0+8], v[n0+12]);
            dft16_twiddles<true>(v);
            // stage 2: emit only time samples n = k0 (k1=0) and k0+4 (k1=1)
            cplx* orow = (cplx*)(out + ((size_t)b*NC + c)*L_SEQ);
            #pragma unroll
            for(int k0=0;k0<4;k0++){
                cplx a=v[4*k0], bb=v[4*k0+1], cc2=v[4*k0+2], d=v[4*k0+3];
                cplx t0=cadd(a,cc2), t1=csub(a,cc2), t2=cadd(bb,d), t3=csub(bb,d);
                orow[t+512*k0]     = cadd(t0,t2);
                orow[t+512*(k0+4)] = make_float2(t1.x - t3.y, t1.y + t3.x);
            }
        }
    }
}

extern "C" void kernel_launch(void* const* d_in, const int* in_sizes, int n_in,
                              void* d_out, int out_size, void* d_ws, size_t ws_size,
                              hipStream_t stream) {
    const float* x    = (const float*)d_in[0];
    const float* kern = (const float*)d_in[1];
    float* out        = (float*)d_out;
    const size_t lds_bytes = (size_t)NFFT * sizeof(cplx);  // 64 KB
    hipLaunchKernelGGL(fftconv_kernel, dim3(NC*2), dim3(NTH), lds_bytes, stream,
                       x, kern, out);
}